// Round 1
// baseline (2973.236 us; speedup 1.0000x reference)
//
#include <hip/hip_runtime.h>

// Problem constants (fixed by the reference).
constexpr int N = 100000;   // nodes
constexpr int E = 1600000;  // edges
constexpr int D = 128;      // feature dim (both layers)
constexpr int M = 5000;     // mask size

// ---------------- degree / normalization ----------------

__global__ void k_init_deg(float* __restrict__ deg) {
    int i = blockIdx.x * 256 + threadIdx.x;
    if (i < N) deg[i] = 1.0f;  // self-loop weight
}

__global__ void k_deg_accum(const int* __restrict__ dst, const float* __restrict__ ew,
                            float* __restrict__ deg) {
    int e = blockIdx.x * 256 + threadIdx.x;
    if (e < E) unsafeAtomicAdd(&deg[dst[e]], ew[e]);
}

__global__ void k_rsqrt(float* __restrict__ deg) {
    int i = blockIdx.x * 256 + threadIdx.x;
    if (i < N) deg[i] = rsqrtf(deg[i]);  // deg >= 1 always, in-place -> dis
}

// ---------------- GEMM: H = X @ W  (row-major, N x D @ D x D) ----------------
// 128 threads/block (one col each), 8 rows per block, X rows staged in LDS.

__global__ __launch_bounds__(128) void k_gemm(const float* __restrict__ X,
                                              const float* __restrict__ W,
                                              float* __restrict__ H) {
    __shared__ float Xs[8 * D];
    const int row0 = blockIdx.x * 8;
    const int col = threadIdx.x;

    const float4* Xv = (const float4*)(X + (size_t)row0 * D);
    float4* Xsv = (float4*)Xs;
    Xsv[col]       = Xv[col];
    Xsv[col + 128] = Xv[col + 128];
    __syncthreads();

    float acc[8] = {0, 0, 0, 0, 0, 0, 0, 0};
#pragma unroll 4
    for (int k = 0; k < D; ++k) {
        float wv = W[k * D + col];
#pragma unroll
        for (int r = 0; r < 8; ++r) acc[r] += Xs[r * D + k] * wv;
    }
#pragma unroll
    for (int r = 0; r < 8; ++r) H[(size_t)(row0 + r) * D + col] = acc[r];
}

// ---------------- edge scatter: agg[dst] += H[src] * norm ----------------
// One edge per 64-lane wave; each lane owns a float2 of the 128-wide row.

__global__ void k_scatter(const float* __restrict__ H, const int* __restrict__ src,
                          const int* __restrict__ dst, const float* __restrict__ ew,
                          const float* __restrict__ dis, float* __restrict__ agg) {
    int t = blockIdx.x * 256 + threadIdx.x;  // E*64 total threads
    int e = t >> 6;
    if (e >= E) return;
    int p = t & 63;
    int s = src[e], d = dst[e];
    float nrm = dis[s] * ew[e] * dis[d];
    float2 v = ((const float2*)(H + (size_t)s * D))[p];
    float* o = agg + (size_t)d * D + p * 2;
    unsafeAtomicAdd(o, v.x * nrm);
    unsafeAtomicAdd(o + 1, v.y * nrm);
}

// ---------------- self-loop + bias (+ optional relu), in place on agg ----------------

__global__ void k_finish(const float* __restrict__ Hpre, const float* __restrict__ dis,
                         const float* __restrict__ b, float* __restrict__ agg, int relu) {
    int i = blockIdx.x * 256 + threadIdx.x;  // N*32 float4 elements
    if (i >= N * (D / 4)) return;
    int node = i >> 5;
    int q = i & 31;
    float sn = dis[node];
    sn = sn * sn;  // dis[n]*1*dis[n] = 1/deg
    float4 hp = ((const float4*)Hpre)[i];
    float4 a  = ((float4*)agg)[i];
    float4 bb = ((const float4*)b)[q];
    a.x = a.x + hp.x * sn + bb.x;
    a.y = a.y + hp.y * sn + bb.y;
    a.z = a.z + hp.z * sn + bb.z;
    a.w = a.w + hp.w * sn + bb.w;
    if (relu) {
        a.x = fmaxf(a.x, 0.f);
        a.y = fmaxf(a.y, 0.f);
        a.z = fmaxf(a.z, 0.f);
        a.w = fmaxf(a.w, 0.f);
    }
    ((float4*)agg)[i] = a;
}

// ---------------- output gather: out = [H2[mask] (f32), (float)y[mask]] ----------------

__global__ void k_gather(const float* __restrict__ H2, const int* __restrict__ mask,
                         const int* __restrict__ y, float* __restrict__ out) {
    int i = blockIdx.x * 256 + threadIdx.x;
    const int nf = M * (D / 4);
    if (i < nf) {
        int r = i >> 5, q = i & 31;
        ((float4*)out)[i] = ((const float4*)(H2 + (size_t)mask[r] * D))[q];
    } else {
        int j = i - nf;
        if (j < M) out[(size_t)M * D + j] = (float)y[mask[j]];
    }
}

extern "C" void kernel_launch(void* const* d_in, const int* in_sizes, int n_in,
                              void* d_out, int out_size, void* d_ws, size_t ws_size,
                              hipStream_t stream) {
    const float* x  = (const float*)d_in[0];
    const float* ew = (const float*)d_in[1];
    const float* W1 = (const float*)d_in[2];
    const float* b1 = (const float*)d_in[3];
    const float* W2 = (const float*)d_in[4];
    const float* b2 = (const float*)d_in[5];
    const int* eidx = (const int*)d_in[6];
    const int* mask = (const int*)d_in[7];
    const int* y    = (const int*)d_in[8];
    const int* src = eidx;       // edge_index[0]
    const int* dst = eidx + E;   // edge_index[1]

    // Workspace layout: deg/dis (N f32) | A (N*D f32) | B (N*D f32)  ~= 98.2 MB
    char* ws = (char*)d_ws;
    float* deg = (float*)ws;
    float* A   = (float*)(ws + 512 * 1024);
    float* B   = (float*)(ws + 512 * 1024 + (size_t)N * D * sizeof(float));

    const size_t featBytes = (size_t)N * D * sizeof(float);

    // Normalization (shared by both layers).
    hipLaunchKernelGGL(k_init_deg, dim3((N + 255) / 256), dim3(256), 0, stream, deg);
    hipLaunchKernelGGL(k_deg_accum, dim3((E + 255) / 256), dim3(256), 0, stream, dst, ew, deg);
    hipLaunchKernelGGL(k_rsqrt, dim3((N + 255) / 256), dim3(256), 0, stream, deg);

    // Layer 1: A = x@W1 ; B = scatter(A) ; B = relu(B + A*selfnorm + b1)
    hipLaunchKernelGGL(k_gemm, dim3(N / 8), dim3(128), 0, stream, x, W1, A);
    hipMemsetAsync(B, 0, featBytes, stream);
    hipLaunchKernelGGL(k_scatter, dim3(E * 64 / 256), dim3(256), 0, stream, A, src, dst, ew, deg, B);
    hipLaunchKernelGGL(k_finish, dim3(N * 32 / 256), dim3(256), 0, stream, A, deg, b1, B, 1);

    // Layer 2: A = B@W2 ; B = scatter(A) ; B = B + A*selfnorm + b2
    hipLaunchKernelGGL(k_gemm, dim3(N / 8), dim3(128), 0, stream, B, W2, A);
    hipMemsetAsync(B, 0, featBytes, stream);
    hipLaunchKernelGGL(k_scatter, dim3(E * 64 / 256), dim3(256), 0, stream, A, src, dst, ew, deg, B);
    hipLaunchKernelGGL(k_finish, dim3(N * 32 / 256), dim3(256), 0, stream, A, deg, b2, B, 0);

    // Output
    hipLaunchKernelGGL(k_gather, dim3((M * 32 + M + 255) / 256), dim3(256), 0, stream,
                       B, mask, y, (float*)d_out);
}

// Round 2
// 837.959 us; speedup vs baseline: 3.5482x; 3.5482x over previous
//
#include <hip/hip_runtime.h>

// Problem constants (fixed by the reference).
constexpr int N = 100000;   // nodes
constexpr int E = 1600000;  // edges
constexpr int D = 128;      // feature dim (both layers)
constexpr int M = 5000;     // mask size

// ---------------- init: deg = 1 (self-loop), count = 0 ----------------

__global__ void k_init(float* __restrict__ deg, int* __restrict__ count) {
    int i = blockIdx.x * 256 + threadIdx.x;
    if (i < N) { deg[i] = 1.0f; count[i] = 0; }
}

// ---------------- deg += ew, count += 1 over dst ----------------

__global__ void k_count_deg(const int* __restrict__ dst, const float* __restrict__ ew,
                            float* __restrict__ deg, int* __restrict__ count) {
    int e = blockIdx.x * 256 + threadIdx.x;
    if (e < E) {
        int d = dst[e];
        unsafeAtomicAdd(&deg[d], ew[e]);
        atomicAdd(&count[d], 1);
    }
}

__global__ void k_rsqrt(float* __restrict__ deg) {
    int i = blockIdx.x * 256 + threadIdx.x;
    if (i < N) deg[i] = rsqrtf(deg[i]);  // deg >= 1 always; in place -> dis
}

// ---------------- exclusive scan of count -> rowStart (N+1), cursor ----------------
// Single 1024-thread block; each thread owns a contiguous chunk.

__global__ __launch_bounds__(1024) void k_scan(const int* __restrict__ count,
                                               int* __restrict__ rowStart,
                                               int* __restrict__ cursor) {
    __shared__ int sums[1024];
    const int tid = threadIdx.x;
    const int per = (N + 1023) / 1024;  // 98
    const int beg = tid * per;
    const int end = min(beg + per, N);
    int s = 0;
    for (int i = beg; i < end; ++i) s += count[i];
    sums[tid] = s;
    __syncthreads();
    for (int off = 1; off < 1024; off <<= 1) {
        int v = (tid >= off) ? sums[tid - off] : 0;
        __syncthreads();
        sums[tid] += v;
        __syncthreads();
    }
    int prefix = (tid == 0) ? 0 : sums[tid - 1];
    for (int i = beg; i < end; ++i) {
        rowStart[i] = prefix;
        cursor[i] = prefix;
        prefix += count[i];
    }
    if (tid == 0) rowStart[N] = E;
}

// ---------------- fill buckets: pairs[pos] = (src, dis[src]*ew) ----------------

__global__ void k_fill(const int* __restrict__ src, const int* __restrict__ dst,
                       const float* __restrict__ ew, const float* __restrict__ dis,
                       int* __restrict__ cursor, int2* __restrict__ pairs) {
    int e = blockIdx.x * 256 + threadIdx.x;
    if (e >= E) return;
    int s = src[e], d = dst[e];
    int pos = atomicAdd(&cursor[d], 1);
    float v = dis[s] * ew[e];
    pairs[pos] = make_int2(s, __float_as_int(v));
}

// ---------------- GEMM: H = X @ W  (row-major, N x D @ D x D) ----------------

__global__ __launch_bounds__(128) void k_gemm(const float* __restrict__ X,
                                              const float* __restrict__ W,
                                              float* __restrict__ H) {
    __shared__ float Xs[8 * D];
    const int row0 = blockIdx.x * 8;
    const int col = threadIdx.x;

    const float4* Xv = (const float4*)(X + (size_t)row0 * D);
    float4* Xsv = (float4*)Xs;
    Xsv[col]       = Xv[col];
    Xsv[col + 128] = Xv[col + 128];
    __syncthreads();

    float acc[8] = {0, 0, 0, 0, 0, 0, 0, 0};
#pragma unroll 4
    for (int k = 0; k < D; ++k) {
        float wv = W[k * D + col];
#pragma unroll
        for (int r = 0; r < 8; ++r) acc[r] += Xs[r * D + k] * wv;
    }
#pragma unroll
    for (int r = 0; r < 8; ++r) H[(size_t)(row0 + r) * D + col] = acc[r];
}

// ---------------- aggregate (all nodes): out[n] = dis[n]*sum + h[n]/deg + b ----------------
// One 64-lane wave per node; lane owns a float2 of the row. No atomics.

__global__ __launch_bounds__(256) void k_aggregate(const float* __restrict__ H,
                                                   const int2* __restrict__ pairs,
                                                   const int* __restrict__ rowStart,
                                                   const float* __restrict__ dis,
                                                   const float* __restrict__ b,
                                                   float* __restrict__ out, int relu) {
    int node = blockIdx.x * 4 + (threadIdx.x >> 6);
    if (node >= N) return;
    int lane = threadIdx.x & 63;
    int beg = rowStart[node], end = rowStart[node + 1];

    float2 acc = make_float2(0.f, 0.f);
    int j = beg;
    for (; j + 1 < end; j += 2) {  // 2 independent gathers in flight
        int2 p0 = pairs[j], p1 = pairs[j + 1];
        float2 h0 = ((const float2*)(H + (size_t)p0.x * D))[lane];
        float2 h1 = ((const float2*)(H + (size_t)p1.x * D))[lane];
        float v0 = __int_as_float(p0.y), v1 = __int_as_float(p1.y);
        acc.x += h0.x * v0 + h1.x * v1;
        acc.y += h0.y * v0 + h1.y * v1;
    }
    if (j < end) {
        int2 p0 = pairs[j];
        float2 h0 = ((const float2*)(H + (size_t)p0.x * D))[lane];
        float v0 = __int_as_float(p0.y);
        acc.x += h0.x * v0;
        acc.y += h0.y * v0;
    }

    float dd = dis[node];
    float sn = dd * dd;  // self-loop norm
    float2 hs = ((const float2*)(H + (size_t)node * D))[lane];
    float2 bb = ((const float2*)b)[lane];
    float ox = acc.x * dd + hs.x * sn + bb.x;
    float oy = acc.y * dd + hs.y * sn + bb.y;
    if (relu) { ox = fmaxf(ox, 0.f); oy = fmaxf(oy, 0.f); }
    ((float2*)(out + (size_t)node * D))[lane] = make_float2(ox, oy);
}

// ---------------- aggregate only mask nodes; write rows + y straight to d_out ----------------

__global__ __launch_bounds__(256) void k_aggregate_mask(const float* __restrict__ H,
                                                        const int2* __restrict__ pairs,
                                                        const int* __restrict__ rowStart,
                                                        const float* __restrict__ dis,
                                                        const float* __restrict__ b,
                                                        const int* __restrict__ mask,
                                                        const int* __restrict__ y,
                                                        float* __restrict__ out) {
    int i = blockIdx.x * 4 + (threadIdx.x >> 6);
    if (i >= M) return;
    int lane = threadIdx.x & 63;
    int node = mask[i];
    int beg = rowStart[node], end = rowStart[node + 1];

    float2 acc = make_float2(0.f, 0.f);
    int j = beg;
    for (; j + 1 < end; j += 2) {
        int2 p0 = pairs[j], p1 = pairs[j + 1];
        float2 h0 = ((const float2*)(H + (size_t)p0.x * D))[lane];
        float2 h1 = ((const float2*)(H + (size_t)p1.x * D))[lane];
        float v0 = __int_as_float(p0.y), v1 = __int_as_float(p1.y);
        acc.x += h0.x * v0 + h1.x * v1;
        acc.y += h0.y * v0 + h1.y * v1;
    }
    if (j < end) {
        int2 p0 = pairs[j];
        float2 h0 = ((const float2*)(H + (size_t)p0.x * D))[lane];
        float v0 = __int_as_float(p0.y);
        acc.x += h0.x * v0;
        acc.y += h0.y * v0;
    }

    float dd = dis[node];
    float sn = dd * dd;
    float2 hs = ((const float2*)(H + (size_t)node * D))[lane];
    float2 bb = ((const float2*)b)[lane];
    float ox = acc.x * dd + hs.x * sn + bb.x;
    float oy = acc.y * dd + hs.y * sn + bb.y;
    ((float2*)(out + (size_t)i * D))[lane] = make_float2(ox, oy);
    if (lane == 0) out[(size_t)M * D + i] = (float)y[node];
}

extern "C" void kernel_launch(void* const* d_in, const int* in_sizes, int n_in,
                              void* d_out, int out_size, void* d_ws, size_t ws_size,
                              hipStream_t stream) {
    const float* x  = (const float*)d_in[0];
    const float* ew = (const float*)d_in[1];
    const float* W1 = (const float*)d_in[2];
    const float* b1 = (const float*)d_in[3];
    const float* W2 = (const float*)d_in[4];
    const float* b2 = (const float*)d_in[5];
    const int* eidx = (const int*)d_in[6];
    const int* mask = (const int*)d_in[7];
    const int* y    = (const int*)d_in[8];
    const int* src = eidx;       // edge_index[0]
    const int* dst = eidx + E;   // edge_index[1]

    // Workspace layout (bytes):
    //   dis      @ 0        : N f32            (0.4 MB)
    //   count    @ 0.5 MB   : N i32            (0.4 MB)
    //   rowStart @ 1.0 MB   : N+1 i32          (0.4 MB)
    //   cursor   @ 1.5 MB   : N i32            (0.4 MB)
    //   pairs    @ 2.0 MB   : E int2           (12.8 MB)
    //   A        @ 16 MB    : N*D f32          (51.2 MB)
    //   B        @ 68 MB    : N*D f32          (51.2 MB)   total ~119.2 MB
    char* ws = (char*)d_ws;
    float* dis     = (float*)(ws);
    int*   count   = (int*)(ws + (size_t)512 * 1024);
    int*   rowStart= (int*)(ws + (size_t)1024 * 1024);
    int*   cursor  = (int*)(ws + (size_t)1536 * 1024);
    int2*  pairs   = (int2*)(ws + (size_t)2048 * 1024);
    float* A       = (float*)(ws + (size_t)16 * 1024 * 1024);
    float* B       = (float*)(ws + (size_t)68 * 1024 * 1024);

    // --- normalization + CSR build (shared by both layers) ---
    hipLaunchKernelGGL(k_init, dim3((N + 255) / 256), dim3(256), 0, stream, dis, count);
    hipLaunchKernelGGL(k_count_deg, dim3((E + 255) / 256), dim3(256), 0, stream, dst, ew, dis, count);
    hipLaunchKernelGGL(k_rsqrt, dim3((N + 255) / 256), dim3(256), 0, stream, dis);
    hipLaunchKernelGGL(k_scan, dim3(1), dim3(1024), 0, stream, count, rowStart, cursor);
    hipLaunchKernelGGL(k_fill, dim3((E + 255) / 256), dim3(256), 0, stream, src, dst, ew, dis, cursor, pairs);

    // --- layer 1: A = x@W1 ; B = relu(aggregate(A) + b1) ---
    hipLaunchKernelGGL(k_gemm, dim3(N / 8), dim3(128), 0, stream, x, W1, A);
    hipLaunchKernelGGL(k_aggregate, dim3((N + 3) / 4), dim3(256), 0, stream,
                       A, pairs, rowStart, dis, b1, B, 1);

    // --- layer 2: A = B@W2 ; out rows = aggregate(A) at mask nodes only ---
    hipLaunchKernelGGL(k_gemm, dim3(N / 8), dim3(128), 0, stream, B, W2, A);
    hipLaunchKernelGGL(k_aggregate_mask, dim3((M + 3) / 4), dim3(256), 0, stream,
                       A, pairs, rowStart, dis, b2, mask, y, (float*)d_out);
}

// Round 3
// 608.103 us; speedup vs baseline: 4.8894x; 1.3780x over previous
//
#include <hip/hip_runtime.h>

// Problem constants (fixed by the reference).
constexpr int N = 100000;   // nodes
constexpr int E = 1600000;  // edges
constexpr int D = 128;      // feature dim (both layers)
constexpr int M = 5000;     // mask size

constexpr int SCHUNK = 1024;                       // scan elements per block
constexpr int SBLK = (N + SCHUNK - 1) / SCHUNK;    // 98 scan blocks

// ---------------- init: deg = 1 (self-loop), count = 0 ----------------

__global__ void k_init(float* __restrict__ deg, int* __restrict__ count) {
    int i = blockIdx.x * 256 + threadIdx.x;
    if (i < N) { deg[i] = 1.0f; count[i] = 0; }
}

// ---------------- deg += ew, count += 1 over dst ----------------

__global__ void k_count_deg(const int* __restrict__ dst, const float* __restrict__ ew,
                            float* __restrict__ deg, int* __restrict__ count) {
    int e = blockIdx.x * 256 + threadIdx.x;
    if (e < E) {
        int d = dst[e];
        unsafeAtomicAdd(&deg[d], ew[e]);
        atomicAdd(&count[d], 1);
    }
}

__global__ void k_rsqrt(float* __restrict__ deg) {
    int i = blockIdx.x * 256 + threadIdx.x;
    if (i < N) deg[i] = rsqrtf(deg[i]);  // deg >= 1 always; in place -> dis
}

// ---------------- parallel scan, phase 1: per-block sums ----------------

__global__ __launch_bounds__(256) void k_scan_partial(const int* __restrict__ count,
                                                      int* __restrict__ blockSums) {
    __shared__ int ws_[4];
    const int t = threadIdx.x;
    const int idx = blockIdx.x * SCHUNK + t * 4;
    int s = 0;
    if (idx + 3 < N) {
        int4 c = *(const int4*)(count + idx);
        s = c.x + c.y + c.z + c.w;
    } else {
        for (int i = 0; i < 4; ++i) if (idx + i < N) s += count[idx + i];
    }
    // wave reduce
    for (int off = 32; off > 0; off >>= 1) s += __shfl_down(s, off);
    if ((t & 63) == 0) ws_[t >> 6] = s;
    __syncthreads();
    if (t == 0) blockSums[blockIdx.x] = ws_[0] + ws_[1] + ws_[2] + ws_[3];
}

// ---------------- scan phase 2: exclusive scan of 98 block sums ----------------

__global__ __launch_bounds__(128) void k_scan_blocksums(int* __restrict__ blockSums,
                                                        int* __restrict__ blockOff,
                                                        int* __restrict__ rowStart) {
    __shared__ int sh[128];
    int t = threadIdx.x;
    int v = (t < SBLK) ? blockSums[t] : 0;
    sh[t] = v;
    __syncthreads();
    for (int off = 1; off < 128; off <<= 1) {
        int u = (t >= off) ? sh[t - off] : 0;
        __syncthreads();
        sh[t] += u;
        __syncthreads();
    }
    if (t < SBLK) blockOff[t] = sh[t] - v;  // exclusive
    if (t == 0) rowStart[N] = E;
}

// ---------------- scan phase 3: final exclusive prefixes -> rowStart, cursor ----------------

__global__ __launch_bounds__(256) void k_scan_final(const int* __restrict__ count,
                                                    const int* __restrict__ blockOff,
                                                    int* __restrict__ rowStart,
                                                    int* __restrict__ cursor) {
    __shared__ int waveS[4];
    const int t = threadIdx.x;
    const int lane = t & 63;
    const int wave = t >> 6;
    const int idx = blockIdx.x * SCHUNK + t * 4;

    int4 c = make_int4(0, 0, 0, 0);
    if (idx + 3 < N) c = *(const int4*)(count + idx);
    else {
        if (idx + 0 < N) c.x = count[idx + 0];
        if (idx + 1 < N) c.y = count[idx + 1];
        if (idx + 2 < N) c.z = count[idx + 2];
        if (idx + 3 < N) c.w = count[idx + 3];
    }
    int s = c.x + c.y + c.z + c.w;

    // inclusive wave scan of s
    int v = s;
    for (int off = 1; off < 64; off <<= 1) {
        int u = __shfl_up(v, off);
        if (lane >= off) v += u;
    }
    if (lane == 63) waveS[wave] = v;
    __syncthreads();
    int waveBase = 0;
    for (int w = 0; w < 4; ++w) if (w < wave) waveBase += waveS[w];
    int excl = blockOff[blockIdx.x] + waveBase + (v - s);  // exclusive prefix at idx

    int4 rs;
    rs.x = excl;
    rs.y = excl + c.x;
    rs.z = excl + c.x + c.y;
    rs.w = excl + c.x + c.y + c.z;
    if (idx + 3 < N) {
        *(int4*)(rowStart + idx) = rs;
        *(int4*)(cursor + idx) = rs;
    } else {
        if (idx + 0 < N) { rowStart[idx + 0] = rs.x; cursor[idx + 0] = rs.x; }
        if (idx + 1 < N) { rowStart[idx + 1] = rs.y; cursor[idx + 1] = rs.y; }
        if (idx + 2 < N) { rowStart[idx + 2] = rs.z; cursor[idx + 2] = rs.z; }
        if (idx + 3 < N) { rowStart[idx + 3] = rs.w; cursor[idx + 3] = rs.w; }
    }
}

// ---------------- fill buckets: pairs[pos] = (src, dis[src]*ew) ----------------

__global__ void k_fill(const int* __restrict__ src, const int* __restrict__ dst,
                       const float* __restrict__ ew, const float* __restrict__ dis,
                       int* __restrict__ cursor, int2* __restrict__ pairs) {
    int e = blockIdx.x * 256 + threadIdx.x;
    if (e >= E) return;
    int s = src[e], d = dst[e];
    int pos = atomicAdd(&cursor[d], 1);
    float v = dis[s] * ew[e];
    pairs[pos] = make_int2(s, __float_as_int(v));
}

// ---------------- GEMM: H = X @ W  (row-major, N x D @ D x D) ----------------

__global__ __launch_bounds__(128) void k_gemm(const float* __restrict__ X,
                                              const float* __restrict__ W,
                                              float* __restrict__ H) {
    __shared__ float Xs[8 * D];
    const int row0 = blockIdx.x * 8;
    const int col = threadIdx.x;

    const float4* Xv = (const float4*)(X + (size_t)row0 * D);
    float4* Xsv = (float4*)Xs;
    Xsv[col]       = Xv[col];
    Xsv[col + 128] = Xv[col + 128];
    __syncthreads();

    float acc[8] = {0, 0, 0, 0, 0, 0, 0, 0};
#pragma unroll 4
    for (int k = 0; k < D; ++k) {
        float wv = W[k * D + col];
#pragma unroll
        for (int r = 0; r < 8; ++r) acc[r] += Xs[r * D + k] * wv;
    }
#pragma unroll
    for (int r = 0; r < 8; ++r) H[(size_t)(row0 + r) * D + col] = acc[r];
}

// ---------------- aggregate (all nodes): out[n] = dis[n]*sum + h[n]/deg + b ----------------
// One 64-lane wave per node; lane owns a float2 of the row. No atomics.

__global__ __launch_bounds__(256) void k_aggregate(const float* __restrict__ H,
                                                   const int2* __restrict__ pairs,
                                                   const int* __restrict__ rowStart,
                                                   const float* __restrict__ dis,
                                                   const float* __restrict__ b,
                                                   float* __restrict__ out, int relu) {
    int node = blockIdx.x * 4 + (threadIdx.x >> 6);
    if (node >= N) return;
    int lane = threadIdx.x & 63;
    int beg = rowStart[node], end = rowStart[node + 1];

    float2 acc = make_float2(0.f, 0.f);
    int j = beg;
    for (; j + 1 < end; j += 2) {  // 2 independent gathers in flight
        int2 p0 = pairs[j], p1 = pairs[j + 1];
        float2 h0 = ((const float2*)(H + (size_t)p0.x * D))[lane];
        float2 h1 = ((const float2*)(H + (size_t)p1.x * D))[lane];
        float v0 = __int_as_float(p0.y), v1 = __int_as_float(p1.y);
        acc.x += h0.x * v0 + h1.x * v1;
        acc.y += h0.y * v0 + h1.y * v1;
    }
    if (j < end) {
        int2 p0 = pairs[j];
        float2 h0 = ((const float2*)(H + (size_t)p0.x * D))[lane];
        float v0 = __int_as_float(p0.y);
        acc.x += h0.x * v0;
        acc.y += h0.y * v0;
    }

    float dd = dis[node];
    float sn = dd * dd;  // self-loop norm
    float2 hs = ((const float2*)(H + (size_t)node * D))[lane];
    float2 bb = ((const float2*)b)[lane];
    float ox = acc.x * dd + hs.x * sn + bb.x;
    float oy = acc.y * dd + hs.y * sn + bb.y;
    if (relu) { ox = fmaxf(ox, 0.f); oy = fmaxf(oy, 0.f); }
    ((float2*)(out + (size_t)node * D))[lane] = make_float2(ox, oy);
}

// ---------------- aggregate only mask nodes; write rows + y straight to d_out ----------------

__global__ __launch_bounds__(256) void k_aggregate_mask(const float* __restrict__ H,
                                                        const int2* __restrict__ pairs,
                                                        const int* __restrict__ rowStart,
                                                        const float* __restrict__ dis,
                                                        const float* __restrict__ b,
                                                        const int* __restrict__ mask,
                                                        const int* __restrict__ y,
                                                        float* __restrict__ out) {
    int i = blockIdx.x * 4 + (threadIdx.x >> 6);
    if (i >= M) return;
    int lane = threadIdx.x & 63;
    int node = mask[i];
    int beg = rowStart[node], end = rowStart[node + 1];

    float2 acc = make_float2(0.f, 0.f);
    int j = beg;
    for (; j + 1 < end; j += 2) {
        int2 p0 = pairs[j], p1 = pairs[j + 1];
        float2 h0 = ((const float2*)(H + (size_t)p0.x * D))[lane];
        float2 h1 = ((const float2*)(H + (size_t)p1.x * D))[lane];
        float v0 = __int_as_float(p0.y), v1 = __int_as_float(p1.y);
        acc.x += h0.x * v0 + h1.x * v1;
        acc.y += h0.y * v0 + h1.y * v1;
    }
    if (j < end) {
        int2 p0 = pairs[j];
        float2 h0 = ((const float2*)(H + (size_t)p0.x * D))[lane];
        float v0 = __int_as_float(p0.y);
        acc.x += h0.x * v0;
        acc.y += h0.y * v0;
    }

    float dd = dis[node];
    float sn = dd * dd;
    float2 hs = ((const float2*)(H + (size_t)node * D))[lane];
    float2 bb = ((const float2*)b)[lane];
    float ox = acc.x * dd + hs.x * sn + bb.x;
    float oy = acc.y * dd + hs.y * sn + bb.y;
    ((float2*)(out + (size_t)i * D))[lane] = make_float2(ox, oy);
    if (lane == 0) out[(size_t)M * D + i] = (float)y[node];
}

extern "C" void kernel_launch(void* const* d_in, const int* in_sizes, int n_in,
                              void* d_out, int out_size, void* d_ws, size_t ws_size,
                              hipStream_t stream) {
    const float* x  = (const float*)d_in[0];
    const float* ew = (const float*)d_in[1];
    const float* W1 = (const float*)d_in[2];
    const float* b1 = (const float*)d_in[3];
    const float* W2 = (const float*)d_in[4];
    const float* b2 = (const float*)d_in[5];
    const int* eidx = (const int*)d_in[6];
    const int* mask = (const int*)d_in[7];
    const int* y    = (const int*)d_in[8];
    const int* src = eidx;       // edge_index[0]
    const int* dst = eidx + E;   // edge_index[1]

    // Workspace layout (bytes):
    //   dis       @ 0        : N f32            (0.4 MB)
    //   count     @ 0.5 MB   : N i32            (0.4 MB)
    //   rowStart  @ 1.0 MB   : N+1 i32          (0.4 MB)
    //   cursor    @ 1.5 MB   : N i32            (0.4 MB)
    //   blockSums @ 2.0 MB   : SBLK i32
    //   blockOff  @ 2.0 MB+4K: SBLK i32
    //   pairs     @ 3.0 MB   : E int2           (12.8 MB)
    //   A         @ 16 MB    : N*D f32          (51.2 MB)
    //   B         @ 68 MB    : N*D f32          (51.2 MB)   total ~119.2 MB
    char* ws = (char*)d_ws;
    float* dis      = (float*)(ws);
    int*   count    = (int*)(ws + (size_t)512 * 1024);
    int*   rowStart = (int*)(ws + (size_t)1024 * 1024);
    int*   cursor   = (int*)(ws + (size_t)1536 * 1024);
    int*   blockSums= (int*)(ws + (size_t)2048 * 1024);
    int*   blockOff = (int*)(ws + (size_t)2048 * 1024 + 4096);
    int2*  pairs    = (int2*)(ws + (size_t)3072 * 1024);
    float* A        = (float*)(ws + (size_t)16 * 1024 * 1024);
    float* B        = (float*)(ws + (size_t)68 * 1024 * 1024);

    // --- normalization + CSR build (shared by both layers) ---
    hipLaunchKernelGGL(k_init, dim3((N + 255) / 256), dim3(256), 0, stream, dis, count);
    hipLaunchKernelGGL(k_count_deg, dim3((E + 255) / 256), dim3(256), 0, stream, dst, ew, dis, count);
    hipLaunchKernelGGL(k_rsqrt, dim3((N + 255) / 256), dim3(256), 0, stream, dis);
    hipLaunchKernelGGL(k_scan_partial, dim3(SBLK), dim3(256), 0, stream, count, blockSums);
    hipLaunchKernelGGL(k_scan_blocksums, dim3(1), dim3(128), 0, stream, blockSums, blockOff, rowStart);
    hipLaunchKernelGGL(k_scan_final, dim3(SBLK), dim3(256), 0, stream, count, blockOff, rowStart, cursor);
    hipLaunchKernelGGL(k_fill, dim3((E + 255) / 256), dim3(256), 0, stream, src, dst, ew, dis, cursor, pairs);

    // --- layer 1: A = x@W1 ; B = relu(aggregate(A) + b1) ---
    hipLaunchKernelGGL(k_gemm, dim3(N / 8), dim3(128), 0, stream, x, W1, A);
    hipLaunchKernelGGL(k_aggregate, dim3((N + 3) / 4), dim3(256), 0, stream,
                       A, pairs, rowStart, dis, b1, B, 1);

    // --- layer 2: A = B@W2 ; out rows = aggregate(A) at mask nodes only ---
    hipLaunchKernelGGL(k_gemm, dim3(N / 8), dim3(128), 0, stream, B, W2, A);
    hipLaunchKernelGGL(k_aggregate_mask, dim3((M + 3) / 4), dim3(256), 0, stream,
                       A, pairs, rowStart, dis, b2, mask, y, (float*)d_out);
}

// Round 4
// 488.389 us; speedup vs baseline: 6.0878x; 1.2451x over previous
//
#include <hip/hip_runtime.h>

// Problem constants (fixed by the reference).
constexpr int N = 100000;   // nodes
constexpr int E = 1600000;  // edges
constexpr int D = 128;      // feature dim (both layers)
constexpr int M = 5000;     // mask size

constexpr int SCHUNK = 1024;                       // scan elements per block
constexpr int SBLK = (N + SCHUNK - 1) / SCHUNK;    // 98 scan blocks

// ---------------- build: one u64 atomic per edge ----------------
// packed[d]: bits [47:0] = sum of ew * 2^30 (fixed point), bits [63:48] = count.
// The returned old value's count field is this edge's rank within its dst bucket.

__global__ void k_build(const int* __restrict__ dst, const float* __restrict__ ew,
                        unsigned long long* __restrict__ packed, int* __restrict__ rank) {
    int e = blockIdx.x * 256 + threadIdx.x;
    if (e >= E) return;
    int d = dst[e];
    unsigned long long val = (1ull << 48) | (unsigned long long)(ew[e] * 1073741824.0f + 0.5f);
    unsigned long long old = atomicAdd(&packed[d], val);
    rank[e] = (int)(old >> 48);
}

// ---------------- unpack: dis = rsqrt(1 + frac*2^-30), count = hi16 ----------------

__global__ void k_unpack(const unsigned long long* __restrict__ packed,
                         float* __restrict__ dis, int* __restrict__ count) {
    int i = blockIdx.x * 256 + threadIdx.x;
    if (i >= N) return;
    unsigned long long p = packed[i];
    count[i] = (int)(p >> 48);
    float deg = 1.0f + (float)((double)(p & 0xFFFFFFFFFFFFull) * (1.0 / 1073741824.0));
    dis[i] = rsqrtf(deg);
}

// ---------------- parallel scan, phase 1: per-block sums ----------------

__global__ __launch_bounds__(256) void k_scan_partial(const int* __restrict__ count,
                                                      int* __restrict__ blockSums) {
    __shared__ int ws_[4];
    const int t = threadIdx.x;
    const int idx = blockIdx.x * SCHUNK + t * 4;
    int s = 0;
    if (idx + 3 < N) {
        int4 c = *(const int4*)(count + idx);
        s = c.x + c.y + c.z + c.w;
    } else {
        for (int i = 0; i < 4; ++i) if (idx + i < N) s += count[idx + i];
    }
    for (int off = 32; off > 0; off >>= 1) s += __shfl_down(s, off);
    if ((t & 63) == 0) ws_[t >> 6] = s;
    __syncthreads();
    if (t == 0) blockSums[blockIdx.x] = ws_[0] + ws_[1] + ws_[2] + ws_[3];
}

// ---------------- scan phase 2: exclusive scan of 98 block sums ----------------

__global__ __launch_bounds__(128) void k_scan_blocksums(int* __restrict__ blockSums,
                                                        int* __restrict__ blockOff,
                                                        int* __restrict__ rowStart) {
    __shared__ int sh[128];
    int t = threadIdx.x;
    int v = (t < SBLK) ? blockSums[t] : 0;
    sh[t] = v;
    __syncthreads();
    for (int off = 1; off < 128; off <<= 1) {
        int u = (t >= off) ? sh[t - off] : 0;
        __syncthreads();
        sh[t] += u;
        __syncthreads();
    }
    if (t < SBLK) blockOff[t] = sh[t] - v;  // exclusive
    if (t == 0) rowStart[N] = E;
}

// ---------------- scan phase 3: final exclusive prefixes -> rowStart ----------------

__global__ __launch_bounds__(256) void k_scan_final(const int* __restrict__ count,
                                                    const int* __restrict__ blockOff,
                                                    int* __restrict__ rowStart) {
    __shared__ int waveS[4];
    const int t = threadIdx.x;
    const int lane = t & 63;
    const int wave = t >> 6;
    const int idx = blockIdx.x * SCHUNK + t * 4;

    int4 c = make_int4(0, 0, 0, 0);
    if (idx + 3 < N) c = *(const int4*)(count + idx);
    else {
        if (idx + 0 < N) c.x = count[idx + 0];
        if (idx + 1 < N) c.y = count[idx + 1];
        if (idx + 2 < N) c.z = count[idx + 2];
        if (idx + 3 < N) c.w = count[idx + 3];
    }
    int s = c.x + c.y + c.z + c.w;

    int v = s;
    for (int off = 1; off < 64; off <<= 1) {
        int u = __shfl_up(v, off);
        if (lane >= off) v += u;
    }
    if (lane == 63) waveS[wave] = v;
    __syncthreads();
    int waveBase = 0;
    for (int w = 0; w < 4; ++w) if (w < wave) waveBase += waveS[w];
    int excl = blockOff[blockIdx.x] + waveBase + (v - s);

    int4 rs;
    rs.x = excl;
    rs.y = excl + c.x;
    rs.z = excl + c.x + c.y;
    rs.w = excl + c.x + c.y + c.z;
    if (idx + 3 < N) {
        *(int4*)(rowStart + idx) = rs;
    } else {
        if (idx + 0 < N) rowStart[idx + 0] = rs.x;
        if (idx + 1 < N) rowStart[idx + 1] = rs.y;
        if (idx + 2 < N) rowStart[idx + 2] = rs.z;
        if (idx + 3 < N) rowStart[idx + 3] = rs.w;
    }
}

// ---------------- fill buckets (NO atomics): pairs[rowStart[d]+rank] = (src, dis[src]*ew) ----------------

__global__ void k_fill(const int* __restrict__ src, const int* __restrict__ dst,
                       const float* __restrict__ ew, const float* __restrict__ dis,
                       const int* __restrict__ rowStart, const int* __restrict__ rank,
                       int2* __restrict__ pairs) {
    int e = blockIdx.x * 256 + threadIdx.x;
    if (e >= E) return;
    int s = src[e], d = dst[e];
    int pos = rowStart[d] + rank[e];
    float v = dis[s] * ew[e];
    pairs[pos] = make_int2(s, __float_as_int(v));
}

// ---------------- GEMM: H = X @ W  (row-major, N x D @ D x D) ----------------
// 128 threads (one col each), 8 rows/block. k chunked by 4: X rows come in as
// broadcast ds_read_b128, W as 4 coalesced dword loads -> 32 FMA per 8 LDS instrs.

__global__ __launch_bounds__(128) void k_gemm(const float* __restrict__ X,
                                              const float* __restrict__ W,
                                              float* __restrict__ H) {
    __shared__ float Xs[8 * D];
    const int row0 = blockIdx.x * 8;
    const int col = threadIdx.x;

    const float4* Xv = (const float4*)(X + (size_t)row0 * D);
    float4* Xsv = (float4*)Xs;
    Xsv[col]       = Xv[col];
    Xsv[col + 128] = Xv[col + 128];
    __syncthreads();

    float acc[8] = {0, 0, 0, 0, 0, 0, 0, 0};
#pragma unroll 4
    for (int kk = 0; kk < D; kk += 4) {
        float w0 = W[(kk + 0) * D + col];
        float w1 = W[(kk + 1) * D + col];
        float w2 = W[(kk + 2) * D + col];
        float w3 = W[(kk + 3) * D + col];
#pragma unroll
        for (int r = 0; r < 8; ++r) {
            float4 xv = *(const float4*)(Xs + r * D + kk);
            acc[r] = fmaf(xv.w, w3, fmaf(xv.z, w2, fmaf(xv.y, w1, fmaf(xv.x, w0, acc[r]))));
        }
    }
#pragma unroll
    for (int r = 0; r < 8; ++r) H[(size_t)(row0 + r) * D + col] = acc[r];
}

// ---------------- aggregate (all nodes): out[n] = dis[n]*sum + h[n]/deg + b ----------------
// One 64-lane wave per node; lane owns a float2 of the row. No atomics.

__global__ __launch_bounds__(256) void k_aggregate(const float* __restrict__ H,
                                                   const int2* __restrict__ pairs,
                                                   const int* __restrict__ rowStart,
                                                   const float* __restrict__ dis,
                                                   const float* __restrict__ b,
                                                   float* __restrict__ out, int relu) {
    int node = blockIdx.x * 4 + (threadIdx.x >> 6);
    if (node >= N) return;
    int lane = threadIdx.x & 63;
    int beg = rowStart[node], end = rowStart[node + 1];
    const float2* Hf = (const float2*)H;

    float2 acc = make_float2(0.f, 0.f);
    int j = beg;
    for (; j + 3 < end; j += 4) {  // 4 independent gathers in flight
        int2 p0 = pairs[j], p1 = pairs[j + 1], p2 = pairs[j + 2], p3 = pairs[j + 3];
        float2 h0 = Hf[(size_t)p0.x * 64 + lane];
        float2 h1 = Hf[(size_t)p1.x * 64 + lane];
        float2 h2 = Hf[(size_t)p2.x * 64 + lane];
        float2 h3 = Hf[(size_t)p3.x * 64 + lane];
        float v0 = __int_as_float(p0.y), v1 = __int_as_float(p1.y);
        float v2 = __int_as_float(p2.y), v3 = __int_as_float(p3.y);
        acc.x += h0.x * v0 + h1.x * v1 + h2.x * v2 + h3.x * v3;
        acc.y += h0.y * v0 + h1.y * v1 + h2.y * v2 + h3.y * v3;
    }
    for (; j < end; ++j) {
        int2 p0 = pairs[j];
        float2 h0 = Hf[(size_t)p0.x * 64 + lane];
        float v0 = __int_as_float(p0.y);
        acc.x += h0.x * v0;
        acc.y += h0.y * v0;
    }

    float dd = dis[node];
    float sn = dd * dd;  // self-loop norm = 1/deg
    float2 hs = Hf[(size_t)node * 64 + lane];
    float2 bb = ((const float2*)b)[lane];
    float ox = acc.x * dd + hs.x * sn + bb.x;
    float oy = acc.y * dd + hs.y * sn + bb.y;
    if (relu) { ox = fmaxf(ox, 0.f); oy = fmaxf(oy, 0.f); }
    ((float2*)(out + (size_t)node * D))[lane] = make_float2(ox, oy);
}

// ---------------- aggregate only mask nodes; write rows + y straight to d_out ----------------

__global__ __launch_bounds__(256) void k_aggregate_mask(const float* __restrict__ H,
                                                        const int2* __restrict__ pairs,
                                                        const int* __restrict__ rowStart,
                                                        const float* __restrict__ dis,
                                                        const float* __restrict__ b,
                                                        const int* __restrict__ mask,
                                                        const int* __restrict__ y,
                                                        float* __restrict__ out) {
    int i = blockIdx.x * 4 + (threadIdx.x >> 6);
    if (i >= M) return;
    int lane = threadIdx.x & 63;
    int node = mask[i];
    int beg = rowStart[node], end = rowStart[node + 1];
    const float2* Hf = (const float2*)H;

    float2 acc = make_float2(0.f, 0.f);
    int j = beg;
    for (; j + 3 < end; j += 4) {
        int2 p0 = pairs[j], p1 = pairs[j + 1], p2 = pairs[j + 2], p3 = pairs[j + 3];
        float2 h0 = Hf[(size_t)p0.x * 64 + lane];
        float2 h1 = Hf[(size_t)p1.x * 64 + lane];
        float2 h2 = Hf[(size_t)p2.x * 64 + lane];
        float2 h3 = Hf[(size_t)p3.x * 64 + lane];
        float v0 = __int_as_float(p0.y), v1 = __int_as_float(p1.y);
        float v2 = __int_as_float(p2.y), v3 = __int_as_float(p3.y);
        acc.x += h0.x * v0 + h1.x * v1 + h2.x * v2 + h3.x * v3;
        acc.y += h0.y * v0 + h1.y * v1 + h2.y * v2 + h3.y * v3;
    }
    for (; j < end; ++j) {
        int2 p0 = pairs[j];
        float2 h0 = Hf[(size_t)p0.x * 64 + lane];
        float v0 = __int_as_float(p0.y);
        acc.x += h0.x * v0;
        acc.y += h0.y * v0;
    }

    float dd = dis[node];
    float sn = dd * dd;
    float2 hs = Hf[(size_t)node * 64 + lane];
    float2 bb = ((const float2*)b)[lane];
    float ox = acc.x * dd + hs.x * sn + bb.x;
    float oy = acc.y * dd + hs.y * sn + bb.y;
    ((float2*)(out + (size_t)i * D))[lane] = make_float2(ox, oy);
    if (lane == 0) out[(size_t)M * D + i] = (float)y[node];
}

extern "C" void kernel_launch(void* const* d_in, const int* in_sizes, int n_in,
                              void* d_out, int out_size, void* d_ws, size_t ws_size,
                              hipStream_t stream) {
    const float* x  = (const float*)d_in[0];
    const float* ew = (const float*)d_in[1];
    const float* W1 = (const float*)d_in[2];
    const float* b1 = (const float*)d_in[3];
    const float* W2 = (const float*)d_in[4];
    const float* b2 = (const float*)d_in[5];
    const int* eidx = (const int*)d_in[6];
    const int* mask = (const int*)d_in[7];
    const int* y    = (const int*)d_in[8];
    const int* src = eidx;       // edge_index[0]
    const int* dst = eidx + E;   // edge_index[1]

    // Workspace layout (bytes):
    //   packed    @ 0        : N u64            (0.8 MB)
    //   dis       @ 1.0 MB   : N f32            (0.4 MB)
    //   count     @ 1.5 MB   : N i32            (0.4 MB)
    //   rowStart  @ 2.0 MB   : N+1 i32          (0.4 MB)
    //   blockSums @ 2.5 MB   : SBLK i32
    //   blockOff  @ 2.5 MB+4K: SBLK i32
    //   pairs     @ 3.0 MB   : E int2           (12.8 MB)
    //   A         @ 16 MB    : N*D f32          (51.2 MB)
    //   B         @ 68 MB    : N*D f32          (51.2 MB)   total ~119.2 MB
    //   rank aliases B (E i32, 6.4 MB): dead after k_fill; B written later.
    char* ws = (char*)d_ws;
    unsigned long long* packed = (unsigned long long*)(ws);
    float* dis      = (float*)(ws + (size_t)1024 * 1024);
    int*   count    = (int*)(ws + (size_t)1536 * 1024);
    int*   rowStart = (int*)(ws + (size_t)2048 * 1024);
    int*   blockSums= (int*)(ws + (size_t)2560 * 1024);
    int*   blockOff = (int*)(ws + (size_t)2560 * 1024 + 4096);
    int2*  pairs    = (int2*)(ws + (size_t)3072 * 1024);
    float* A        = (float*)(ws + (size_t)16 * 1024 * 1024);
    float* B        = (float*)(ws + (size_t)68 * 1024 * 1024);
    int*   rank     = (int*)B;  // aliased; see lifetime note above

    // --- CSR build (one u64 atomic per edge; rank from returned old value) ---
    hipMemsetAsync(packed, 0, (size_t)N * sizeof(unsigned long long), stream);
    hipLaunchKernelGGL(k_build, dim3((E + 255) / 256), dim3(256), 0, stream, dst, ew, packed, rank);
    hipLaunchKernelGGL(k_unpack, dim3((N + 255) / 256), dim3(256), 0, stream, packed, dis, count);
    hipLaunchKernelGGL(k_scan_partial, dim3(SBLK), dim3(256), 0, stream, count, blockSums);
    hipLaunchKernelGGL(k_scan_blocksums, dim3(1), dim3(128), 0, stream, blockSums, blockOff, rowStart);
    hipLaunchKernelGGL(k_scan_final, dim3(SBLK), dim3(256), 0, stream, count, blockOff, rowStart);
    hipLaunchKernelGGL(k_fill, dim3((E + 255) / 256), dim3(256), 0, stream,
                       src, dst, ew, dis, rowStart, rank, pairs);

    // --- layer 1: A = x@W1 ; B = relu(aggregate(A) + b1) ---
    hipLaunchKernelGGL(k_gemm, dim3(N / 8), dim3(128), 0, stream, x, W1, A);
    hipLaunchKernelGGL(k_aggregate, dim3((N + 3) / 4), dim3(256), 0, stream,
                       A, pairs, rowStart, dis, b1, B, 1);

    // --- layer 2: A = B@W2 ; out rows = aggregate(A) at mask nodes only ---
    hipLaunchKernelGGL(k_gemm, dim3(N / 8), dim3(128), 0, stream, B, W2, A);
    hipLaunchKernelGGL(k_aggregate_mask, dim3((M + 3) / 4), dim3(256), 0, stream,
                       A, pairs, rowStart, dis, b2, mask, y, (float*)d_out);
}